// Round 10
// baseline (259.003 us; speedup 1.0000x reference)
//
#include <hip/hip_runtime.h>
#include <stdint.h>

// ksparse: per row of 4096x8192 f32, threshold = 513th largest (k=512),
// out = x * (x > thresh). Monolithic single-read/single-write exact
// radix-select, SOFTWARE-PIPELINED over RPB rows per block: next row's
// global loads are issued right after the current row's map, so they fly
// during the select phase (kills the load/select/write convoy measured in
// R6-R9). Tail passes run in wave 0 only (no barriers). 6 barriers/row.

constexpr int COLS  = 8192;
constexpr int TPB   = 256;
constexpr int EPT   = COLS / TPB;  // 32 elements per thread
constexpr int VPT   = EPT / 4;     // 8 float4 per thread
constexpr int NBIN0 = 2048;        // main-pass bins (11 bits)
constexpr int CAP   = 2048;        // candidate buffer (reuses replica 1)
constexpr int RPB   = 4;           // rows per block (pipelined)

__device__ __forceinline__ uint32_t map_f32(uint32_t u) {
  return (u & 0x80000000u) ? ~u : (u | 0x80000000u);
}
__device__ __forceinline__ float unmap_f32(uint32_t m) {
  return __uint_as_float((m & 0x80000000u) ? (m ^ 0x80000000u) : ~m);
}

__global__ __launch_bounds__(TPB, 4)
void ksparse_kernel(const float* __restrict__ in, const int* __restrict__ kptr,
                    float* __restrict__ out, int rows) {
  __shared__ __align__(16) uint32_t hist[2 * NBIN0]; // replica0 | replica1(->cand)
  __shared__ uint32_t th[128];     // tail histogram (wave 0 only)
  __shared__ uint32_t wtot[4];
  __shared__ uint32_t s_packed;
  __shared__ uint32_t s_cnt;
  __shared__ uint32_t s_T;

  const int t    = threadIdx.x;
  const int wave = t >> 6;
  const int lane = t & 63;
  const int row0 = blockIdx.x * RPB;
  const uint32_t krank = (uint32_t)(*kptr) + 1u; // rank from top (513)

  // preamble: zero LDS, load row0
  uint4* h4 = (uint4*)hist;
#pragma unroll
  for (int i = 0; i < 4; ++i) h4[t + i * TPB] = make_uint4(0u, 0u, 0u, 0u);
  if (t == 0) { s_packed = 0u; s_cnt = 0u; }

  float4 v[VPT];
  if (row0 < rows) {
    const float4* inp = (const float4*)(in + (size_t)row0 * COLS);
#pragma unroll
    for (int i = 0; i < VPT; ++i) v[i] = inp[t + i * TPB];
  }
  __syncthreads(); // B1: zeroing done

#pragma unroll 1
  for (int i = 0; i < RPB; ++i) {
    const int r = row0 + i;
    if (r >= rows) break; // block-uniform

    // ---- map current row (frees v), then histogram ----
    uint32_t m[EPT];
#pragma unroll
    for (int j = 0; j < VPT; ++j) {
      m[4 * j + 0] = map_f32(__float_as_uint(v[j].x));
      m[4 * j + 1] = map_f32(__float_as_uint(v[j].y));
      m[4 * j + 2] = map_f32(__float_as_uint(v[j].z));
      m[4 * j + 3] = map_f32(__float_as_uint(v[j].w));
    }

    // ---- prefetch next row NOW; lands during select ----
    if (i + 1 < RPB && r + 1 < rows) {
      const float4* inn = (const float4*)(in + (size_t)(r + 1) * COLS);
#pragma unroll
      for (int j = 0; j < VPT; ++j) v[j] = inn[t + j * TPB];
    }

    uint32_t* h = &hist[(wave >> 1) * NBIN0];
#pragma unroll
    for (int j = 0; j < EPT; ++j) atomicAdd(&h[m[j] >> 21], 1u);
    __syncthreads(); // B2: histogram done

    // ---- scan: 8 bins/thread, wave suffix, packed argmax ----
    uint32_t excl, sl0;
    {
      const uint4* hv = (const uint4*)hist;
      uint4 a0 = hv[2 * t], a1 = hv[2 * t + 1];
      uint4 b0 = hv[512 + 2 * t], b1 = hv[512 + 2 * t + 1];
      uint32_t c0 = a0.x + b0.x, c1 = a0.y + b0.y, c2 = a0.z + b0.z, c3 = a0.w + b0.w;
      uint32_t c4 = a1.x + b1.x, c5 = a1.y + b1.y, c6 = a1.z + b1.z, c7 = a1.w + b1.w;
      uint32_t sl[8];
      sl[7] = c7;         sl[6] = sl[7] + c6; sl[5] = sl[6] + c5; sl[4] = sl[5] + c4;
      sl[3] = sl[4] + c3; sl[2] = sl[3] + c2; sl[1] = sl[2] + c1; sl[0] = sl[1] + c0;
      const uint32_t total = sl[0];

      uint32_t s = total;
#pragma unroll
      for (int off = 1; off < 64; off <<= 1) {
        uint32_t tmp = __shfl_down(s, off, 64);
        s += (lane + off < 64) ? tmp : 0u;
      }
      if (lane == 0) wtot[wave] = s;
      __syncthreads(); // B3

      uint32_t hi = 0;
#pragma unroll
      for (int w = 1; w < 4; ++w)
        if (w > wave) hi += wtot[w];
      excl = hi + (s - total);
      sl0 = total;

      int best = -1;
#pragma unroll
      for (int j = 7; j >= 0; --j)
        if (best < 0 && excl + sl[j] >= krank) best = j;
      if (best >= 0) {
        const uint32_t above = excl + ((best < 7) ? sl[best + 1] : 0u);
        atomicMax(&s_packed, ((uint32_t)(t * 8 + best) << 14) | above);
      }
    }
    __syncthreads(); // B4

    const uint32_t pk = s_packed;
    const uint32_t d0 = pk >> 14;

    // ---- compact candidates into dead replica-1 LDS ----
    uint32_t* cand = &hist[NBIN0];
#pragma unroll
    for (int j = 0; j < EPT; ++j) {
      if ((m[j] >> 21) == d0) {
        uint32_t idx = atomicAdd(&s_cnt, 1u);
        if (idx < CAP) cand[idx] = m[j] & 0x1FFFFFu;
      }
    }
    __syncthreads(); // B5: compaction done

    // ---- wave-0-only tail: three 7-bit passes, NO barriers inside ----
    if (wave == 0) {
      uint32_t kk = krank - (pk & 0x3FFFu);
      const uint32_t Cc = (s_cnt < (uint32_t)CAP) ? s_cnt : (uint32_t)CAP;
      uint32_t tpref = 0;
#pragma unroll 1
      for (int j = 0; j < 3; ++j) {
        const int dsh = 14 - 7 * j;
        th[lane] = 0u; th[64 + lane] = 0u;
        for (uint32_t idx = lane; idx < Cc; idx += 64) {
          const uint32_t c = cand[idx];
          const bool ok = (j == 0) || ((c >> (dsh + 7)) == tpref);
          if (ok) atomicAdd(&th[(c >> dsh) & 127u], 1u);
        }
        uint32_t a = th[lane], b = th[64 + lane];
        uint32_t sb = b, sa = a;
#pragma unroll
        for (int off = 1; off < 64; off <<= 1) {
          uint32_t t1 = __shfl_down(sb, off, 64);
          uint32_t t2 = __shfl_down(sa, off, 64);
          const bool inr = (lane + off < 64);
          sb += inr ? t1 : 0u;
          sa += inr ? t2 : 0u;
        }
        const uint32_t tb = __shfl(sb, 0, 64);
        sa += tb;
        const unsigned long long mb = __ballot(sb >= kk);
        uint32_t d, ab;
        if (mb) {
          const int hb = 63 - __builtin_clzll(mb);
          const uint32_t nx = __shfl(sb, (hb + 1) & 63, 64);
          d = 64 + (uint32_t)hb;
          ab = (hb == 63) ? 0u : nx;
        } else {
          const unsigned long long ma = __ballot(sa >= kk);
          const int ha = 63 - __builtin_clzll(ma);
          const uint32_t nx = __shfl(sa, (ha + 1) & 63, 64);
          d = (uint32_t)ha;
          ab = (ha == 63) ? tb : nx;
        }
        tpref = (tpref << 7) | d;
        kk -= ab;
      }
      if (lane == 0) s_T = (d0 << 21) | tpref;
    }
    __syncthreads(); // B6: T published (also: cand reads done)

    const uint32_t T = s_T;

    // ---- masked store of row r (fire and forget) ----
    float4* op = (float4*)(out + (size_t)r * COLS);
#pragma unroll
    for (int j = 0; j < VPT; ++j) {
      float4 w;
      uint32_t mm;
      mm = m[4 * j + 0]; w.x = (mm > T) ? unmap_f32(mm) : 0.0f;
      mm = m[4 * j + 1]; w.y = (mm > T) ? unmap_f32(mm) : 0.0f;
      mm = m[4 * j + 2]; w.z = (mm > T) ? unmap_f32(mm) : 0.0f;
      mm = m[4 * j + 3]; w.w = (mm > T) ? unmap_f32(mm) : 0.0f;
      op[t + j * TPB] = w;
    }

    // ---- re-zero for next row (replica1/cand safe to clobber after B6) ----
    if (i + 1 < RPB) {
#pragma unroll
      for (int j = 0; j < 4; ++j) h4[t + j * TPB] = make_uint4(0u, 0u, 0u, 0u);
      if (t == 0) { s_packed = 0u; s_cnt = 0u; }
      __syncthreads(); // B1': zero done before next row's atomics
    }
  }
}

extern "C" void kernel_launch(void* const* d_in, const int* in_sizes, int n_in,
                              void* d_out, int out_size, void* d_ws, size_t ws_size,
                              hipStream_t stream) {
  const float* in  = (const float*)d_in[0];
  const int*   k   = (const int*)d_in[1];
  float*       out = (float*)d_out;
  int rows = in_sizes[0] / COLS;
  if (rows < 1) rows = 1;
  const int grid = (rows + RPB - 1) / RPB;
  ksparse_kernel<<<grid, TPB, 0, stream>>>(in, k, out, rows);
}